// Round 6
// baseline (218.018 us; speedup 1.0000x reference)
//
#include <hip/hip_runtime.h>
#include <hip/hip_bf16.h>

#define BLOCK   1024    // 16 waves
#define NSAMP   16      // samples per block (= N of each MFMA tile)
#define HDIM    128
#define DDIM    16
#define NOBJ    6
#define NSLOT   16      // shared h/c slot pool

typedef __attribute__((ext_vector_type(8))) short bf16x8;
typedef __attribute__((ext_vector_type(4))) float f32x4;

constexpr int pc6(int m)  { int c = 0; for (int i = 0; i < 6; ++i) c += (m >> i) & 1; return c; }
constexpr int msb6(int m) { int b = -1; for (int i = 0; i < 6; ++i) if (m & (1 << i)) b = i; return b; }

// Compile-time BFS plan with 16-slot allocator.
// Node: subset mask M; appended obj jo=msb(M); childful iff jo<5.
// Phase 1: leaves + childful children into free slots. Phase 2 (after barrier):
// remaining childful children reuse slots of parents whose children are all
// leaves (= parents with msb==4). Only L3 actually needs phase 2 (10 parents
// live, 6 free slots, 4 freed msb==4 parents).
struct NodeRec { int jo, ps, sl; };
struct Plan { int cnt[7]; int n1[7]; NodeRec nd[7][20]; };
constexpr Plan make_plan() {
    Plan P{};
    int slotOf[64] = {};
    bool busy[NSLOT] = {};
    for (int d = 1; d <= 6; ++d) {
        int n = 0;
        for (int M = 1; M < 64; ++M) {            // phase 1a: leaf children
            if (pc6(M) != d || msb6(M) != 5) continue;
            P.nd[d][n].jo = 5;
            P.nd[d][n].ps = (d == 1) ? -1 : slotOf[M & ~(1 << 5)];
            P.nd[d][n].sl = -1;
            ++n;
        }
        int pend[20] = {}; int np = 0;            // phase 1b: childful into free slots
        for (int M = 1; M < 64; ++M) {
            if (pc6(M) != d || msb6(M) >= 5) continue;
            const int hi = msb6(M);
            int fs = -1;
            for (int s = 0; s < NSLOT; ++s) if (!busy[s]) { fs = s; break; }
            if (fs >= 0) {
                busy[fs] = true; slotOf[M] = fs;
                P.nd[d][n].jo = hi;
                P.nd[d][n].ps = (d == 1) ? -1 : slotOf[M & ~(1 << hi)];
                P.nd[d][n].sl = fs;
                ++n;
            } else pend[np++] = M;
        }
        P.n1[d] = n;
        int freeds[20] = {}; int nf = 0;          // phase 2: reuse msb==4 parents' slots
        if (d >= 2)
            for (int M = 1; M < 64; ++M)
                if (pc6(M) == d - 1 && msb6(M) == 4) freeds[nf++] = slotOf[M];
        for (int i = 0; i < np; ++i) {
            const int M = pend[i]; const int hi = msb6(M);
            const int s = freeds[--nf];
            slotOf[M] = s;
            P.nd[d][n].jo = hi;
            P.nd[d][n].ps = slotOf[M & ~(1 << hi)];
            P.nd[d][n].sl = s;
            ++n;
        }
        P.cnt[d] = n;
        for (int s = 0; s < NSLOT; ++s) busy[s] = false;   // busy = this level's cf slots
        for (int M = 1; M < 64; ++M)
            if (pc6(M) == d && msb6(M) < 5) busy[slotOf[M]] = true;
    }
    return P;
}
constexpr Plan PL = make_plan();

#define LOG2E   1.44269504f
#define TWOL2E  2.88539008f
#define SLOT_SH (16 * NSAMP * 8)   // shorts per slot (4 KB)

__device__ __forceinline__ float fast_sig(float z) {
    float e = __builtin_amdgcn_exp2f(-LOG2E * z);
    return __builtin_amdgcn_rcpf(1.0f + e);
}
__device__ __forceinline__ float fast_tanh(float z) {
    float e = __builtin_amdgcn_exp2f(TWOL2E * z);
    float r = __builtin_amdgcn_rcpf(1.0f + e);
    return fmaf(-2.0f, r, 1.0f);
}
__device__ __forceinline__ unsigned short f2bf(float x) {
    union { float f; unsigned int u; } a; a.f = x;
    unsigned int r = (a.u + 0x7FFFu + ((a.u >> 16) & 1u)) >> 16;
    return (unsigned short)r;
}

// LDS h layout: hs[((slot*16 + kslot)*NSAMP + n)*8 + j] = h[chan = kslot*8+j][sample n]
// B-frag chunk q, lane (quad, n=m16): kslot = q*4+quad -> 16B-aligned ds_read_b128.
// Wave w writes its channels (w*8 + 2*quad, +1) at kslot = w, j = 2*quad.

__global__ __launch_bounds__(BLOCK)
void subset_lstm_w16_kernel(
    const float* __restrict__ x_input,
    const float* __restrict__ W_ih,
    const float* __restrict__ W_hh,
    const float* __restrict__ b_ih,
    const float* __restrict__ b_hh,
    const float* __restrict__ fc1_W,
    const float* __restrict__ fc1_b,
    const float* __restrict__ fc2_W,
    const float* __restrict__ fc2_b,
    float* __restrict__ out)
{
    __shared__ __align__(16) unsigned short hs[NSLOT * SLOT_SH];        // 64 KB
    __shared__ __align__(16) unsigned short xb[NOBJ * 2 * NSAMP * 8];   // 3 KB
    __shared__ __align__(16) unsigned short xpad[16];                   // quad2 {1,0..}, quad3 zeros
    float* s_maxh  = (float*)hs;                 // 8 KB   (post-LSTM alias)
    float* s_fc1   = (float*)(hs + 4096);        // 16 KB  (post-LSTM alias)
    float* s_logit = (float*)xb;

    const int t      = threadIdx.x;
    const int w      = t >> 6;         // wave 0..15: channels cb..cb+7, all 4 gates
    const int lane   = t & 63;
    const int quad   = lane >> 4;
    const int m16    = lane & 15;
    const int cb     = w * 8;
    const int s_base = blockIdx.x * NSAMP;

    if (t < 16) xpad[t] = (t == 0) ? f2bf(1.0f) : (unsigned short)0;

    // ---- x B-chunks (quads 0,1 only; 2,3 come from xpad) ----
    for (int idx = t; idx < NOBJ * 2 * NSAMP * 8; idx += BLOCK) {
        const int j = idx & 7, n = (idx >> 3) & 15, q = (idx >> 7) & 1, obj = idx >> 8;
        xb[idx] = f2bf(x_input[(s_base + n) * (NOBJ * DDIM) + obj * DDIM + q * 8 + j]);
    }

    // ---- persistent A-frags: wf[tile][chunk]; tile0 = {i,f}, tile1 = {g,o} ----
    // A[m=lane&15][k=quad*8+j]; row m -> chan cb+(m>>1), gate 2*T+(m&1)
    bf16x8 wf[2][5];
    #pragma unroll
    for (int T = 0; T < 2; ++T) {
        const int chan = cb + (m16 >> 1);
        const int gate = 2 * T + (m16 & 1);
        const int grow = gate * HDIM + chan;
        const float* whr = W_hh + grow * HDIM;
        const float* wir = W_ih + grow * DDIM;
        #pragma unroll
        for (int q = 0; q < 4; ++q) {
            union { unsigned short u[8]; bf16x8 v; } pk;
            #pragma unroll
            for (int j = 0; j < 8; ++j)
                pk.u[j] = f2bf(whr[q * 32 + quad * 8 + j]);
            wf[T][q] = pk.v;
        }
        {   // x chunk; bias folded at k-local 16 (quad2, j0) against B's 1.0
            union { unsigned short u[8]; bf16x8 v; } pk;
            #pragma unroll
            for (int j = 0; j < 8; ++j) {
                float v = 0.0f;
                if (quad < 2) v = wir[quad * 8 + j];
                else if (quad == 2 && j == 0) v = b_ih[grow] + b_hh[grow];
                pk.u[j] = f2bf(v);
            }
            wf[T][4] = pk.v;
        }
    }

    float cs[NSLOT][2];   // c-state, f32, static slot indices
    float mh0 = -1e30f, mh1 = -1e30f;

    #pragma unroll
    for (int d = 1; d <= 6; ++d) {
        __syncthreads();
        #pragma unroll
        for (int ni = 0; ni < PL.cnt[d]; ++ni) {
            if (ni == PL.n1[d]) __syncthreads();   // L3 slot-recycle barrier (constexpr)
            const int jo = PL.nd[d][ni].jo;
            const int ps = PL.nd[d][ni].ps;
            const int sl = PL.nd[d][ni].sl;

            f32x4 aIF = f32x4{0.f, 0.f, 0.f, 0.f};
            f32x4 aGO = f32x4{0.f, 0.f, 0.f, 0.f};

            {   // x + bias chunk
                const unsigned short* bp = (quad < 2)
                    ? &xb[((jo * 2 + quad) * NSAMP + m16) * 8]
                    : &xpad[(quad - 2) * 8];
                const bf16x8 bfx = *(const bf16x8*)bp;
                aIF = __builtin_amdgcn_mfma_f32_16x16x32_bf16(wf[0][4], bfx, aIF, 0, 0, 0);
                aGO = __builtin_amdgcn_mfma_f32_16x16x32_bf16(wf[1][4], bfx, aGO, 0, 0, 0);
            }
            if (ps >= 0) {
                #pragma unroll
                for (int q = 0; q < 4; ++q) {
                    const bf16x8 bh = *(const bf16x8*)
                        &hs[ps * SLOT_SH + (((q * 4 + quad) * NSAMP) + m16) * 8];
                    aIF = __builtin_amdgcn_mfma_f32_16x16x32_bf16(wf[0][q], bh, aIF, 0, 0, 0);
                    aGO = __builtin_amdgcn_mfma_f32_16x16x32_bf16(wf[1][q], bh, aGO, 0, 0, 0);
                }
            }

            // pointwise: u=0,1 -> channel cb + 2*quad + u, sample m16
            float hnv[2];
            #pragma unroll
            for (int u = 0; u < 2; ++u) {
                const float zi = aIF[2 * u], zf = aIF[2 * u + 1];
                const float zg = aGO[2 * u], zo = aGO[2 * u + 1];
                const float cprev = (ps >= 0) ? cs[ps][u] : 0.0f;
                const float ig = fast_sig(zi);
                const float fg = fast_sig(zf);
                const float gg = fast_tanh(zg);
                const float og = fast_sig(zo);
                const float cn = fmaf(fg, cprev, ig * gg);
                const float h  = og * fast_tanh(cn);
                hnv[u] = h;
                if (sl >= 0) cs[sl][u] = cn;
            }
            mh0 = fmaxf(mh0, hnv[0]);
            mh1 = fmaxf(mh1, hnv[1]);

            if (sl >= 0) {
                const __hip_bfloat162 hp = __float22bfloat162_rn(float2{hnv[0], hnv[1]});
                *(__hip_bfloat162*)&hs[sl * SLOT_SH + ((w * NSAMP) + m16) * 8 + 2 * quad] = hp;
            }
        }
    }

    __syncthreads();   // h slots dead; reuse hs for epilogue
    {
        float2 v; v.x = mh0; v.y = mh1;
        *(float2*)&s_maxh[m16 * HDIM + cb + 2 * quad] = v;
    }
    __syncthreads();

    // ---- FC1: f = t&255, sample group t>>8 (4 samples each) ----
    {
        const int f  = t & 255;
        const int sh = t >> 8;          // 0..3
        float a1[4];
        #pragma unroll
        for (int s = 0; s < 4; ++s) a1[s] = fc1_b[f];
        for (int k4 = 0; k4 < HDIM / 4; ++k4) {
            const float4 wv = *(const float4*)&fc1_W[f * HDIM + k4 * 4];
            #pragma unroll
            for (int s = 0; s < 4; ++s) {
                const float4 h4 = *(const float4*)&s_maxh[(sh * 4 + s) * HDIM + k4 * 4];
                a1[s] += wv.x * h4.x + wv.y * h4.y + wv.z * h4.z + wv.w * h4.w;
            }
        }
        #pragma unroll
        for (int s = 0; s < 4; ++s)
            s_fc1[(sh * 4 + s) * 256 + f] = fmaxf(a1[s], 0.0f);
    }
    __syncthreads();

    if (t < NSAMP * 10) {
        const int s = t / 10, a = t % 10;
        float acc2 = fc2_b[a];
        for (int f4 = 0; f4 < 256 / 4; ++f4) {
            const float4 wv = *(const float4*)&fc2_W[a * 256 + f4 * 4];
            const float4 v  = *(const float4*)&s_fc1[s * 256 + f4 * 4];
            acc2 += wv.x * v.x + wv.y * v.y + wv.z * v.z + wv.w * v.w;
        }
        s_logit[s * 10 + a] = acc2;
    }
    __syncthreads();

    if (t < NSAMP) {
        float m = -1e30f;
        #pragma unroll
        for (int a = 0; a < 10; ++a) m = fmaxf(m, s_logit[t * 10 + a]);
        float sum = 0.0f;
        #pragma unroll
        for (int a = 0; a < 10; ++a) sum += __expf(s_logit[t * 10 + a] - m);
        const float lse = m + __logf(sum);
        #pragma unroll
        for (int a = 0; a < 10; ++a)
            out[(s_base + t) * 10 + a] = s_logit[t * 10 + a] - lse;
    }
}

extern "C" void kernel_launch(void* const* d_in, const int* in_sizes, int n_in,
                              void* d_out, int out_size, void* d_ws, size_t ws_size,
                              hipStream_t stream)
{
    (void)d_ws; (void)ws_size; (void)n_in; (void)out_size;

    const float* x   = (const float*)d_in[0];
    const float* Wih = (const float*)d_in[1];
    const float* Whh = (const float*)d_in[2];
    const float* bih = (const float*)d_in[3];
    const float* bhh = (const float*)d_in[4];
    const float* f1w = (const float*)d_in[5];
    const float* f1b = (const float*)d_in[6];
    const float* f2w = (const float*)d_in[7];
    const float* f2b = (const float*)d_in[8];

    const int mb = in_sizes[0] / (NOBJ * DDIM);   // 8192
    dim3 grid(mb / NSAMP), block(BLOCK);
    subset_lstm_w16_kernel<<<grid, block, 0, stream>>>(
        x, Wih, Whh, bih, bhh, f1w, f1b, f2w, f2b, (float*)d_out);
}